// Round 9
// baseline (403.143 us; speedup 1.0000x reference)
//
#include <hip/hip_runtime.h>
#include <hip/hip_bf16.h>

constexpr int N_NODES = 100000;
constexpr int N_REL   = 4;
constexpr int N_EDGES = 600000;
constexpr int MAXDEG  = 32;          // Poisson(6): P(deg>=32) ~ 7e-14 per node
constexpr int D       = 128;
constexpr int KTOT    = N_REL * D;   // 512 concat cols of A
constexpr int M_PAD   = 100096;      // 1564 gemm blocks * 64 rows

// ---- bucketed-build geometry ----
constexpr int NB   = 128;            // buckets per relation
constexpr int BW   = 784;            // node width per bucket (128*784 = 100352 >= 100000)
constexpr int NKEY = N_REL * NB;     // 512 (r,bucket) keys
constexpr int CAP  = 5632;           // per-bucket capacity: mu=4704, sigma=68 -> +13.6 sigma
constexpr int EPB1 = 4096;           // edges per pass-1 block
constexpr int TOT_E   = N_REL * N_EDGES;              // 2.4M
constexpr int B1_BLKS = (TOT_E + EPB1 - 1) / EPB1;    // 586
constexpr int XC_BLKS = (N_NODES * D / 4) / 256;      // 12500
constexpr int WC_BLKS = (N_REL * D * D) / 256;        // 256

typedef __attribute__((ext_vector_type(8))) short bf16x8;   // MFMA A/B frag (4 VGPRs)
typedef __attribute__((ext_vector_type(4))) float f32x4;    // MFMA C/D frag

static __device__ __forceinline__ unsigned short f2bf(float f) {
    union { float f; unsigned int u; } v; v.f = f;
    unsigned int r = (v.u + 0x7fffu + ((v.u >> 16) & 1u)) >> 16;  // RNE
    return (unsigned short)r;
}

// ---------------------------------------------------------------------------
// 1) Pass 1 (counting-sort): per 4096-edge block, per side (dst/src): rank
//    via LDS histogram -> ONE reservation atomic per (block,key) -> place
//    records bucket-ordered in LDS -> coalesced write-out. Casts ride along.
// ---------------------------------------------------------------------------
__global__ __launch_bounds__(256) void pass1(const int* __restrict__ edges,
                                             int* __restrict__ gcur,        // [2*NKEY*16] padded counters
                                             unsigned* __restrict__ bktd,   // [NKEY*CAP] packed (src,dstloc)
                                             unsigned* __restrict__ bkts,   // [NKEY*CAP] src only
                                             const float* __restrict__ X,
                                             unsigned short* __restrict__ Xb,
                                             const float* __restrict__ W,
                                             unsigned short* __restrict__ Wt) {
    int b = blockIdx.x;
    if (b < B1_BLKS) {
        __shared__ unsigned kr[EPB1];         // 16KB per-slot stash
        __shared__ unsigned sorted[EPB1];     // 16KB records by position
        __shared__ unsigned short keyp[EPB1]; // 8KB  key by position
        __shared__ int h[NKEY], gb[NKEY], pfx[NKEY + 1];
        __shared__ int wsum[4];
        int tid  = threadIdx.x;
        int lane = tid & 63, wv = tid >> 6;
        int e0   = b * EPB1;
        int nval = min(EPB1, TOT_E - e0);

        for (int side = 0; side < 2; side++) {
            for (int k = tid; k < NKEY; k += 256) h[k] = 0;
            __syncthreads();
            // -- phase 1: rank assignment + stash --
            for (int i = tid; i < EPB1; i += 256) {
                unsigned v = 0xFFFFFFFFu;
                if (i < nval) {
                    int t = e0 + i;
                    int r = t / N_EDGES, e = t - r * N_EDGES;
                    if (side == 0) {
                        int dst = edges[(size_t)(r * 2 + 1) * N_EDGES + e];
                        int bkt = dst / BW;
                        int dstloc = dst - bkt * BW;
                        int rank = atomicAdd(&h[r * NB + bkt], 1);
                        v = ((unsigned)bkt << 22) | ((unsigned)dstloc << 12) | (unsigned)rank;
                    } else {
                        int src = edges[(size_t)(r * 2) * N_EDGES + e];
                        int bkt = src / BW;
                        int rank = atomicAdd(&h[r * NB + bkt], 1);
                        v = ((unsigned)src << 12) | (unsigned)rank;
                    }
                }
                kr[i] = v;
            }
            __syncthreads();
            // -- phase 2: global reservation + parallel prefix over h --
            for (int k = tid; k < NKEY; k += 256) {
                int c = h[k];
                gb[k] = c ? atomicAdd(&gcur[(side * NKEY + k) * 16], c) : 0;
            }
            int a0 = h[2 * tid], a1 = h[2 * tid + 1];
            int s  = a0 + a1;
            int incl = s;
#pragma unroll
            for (int dlt = 1; dlt < 64; dlt <<= 1) {
                int n = __shfl_up(incl, dlt);
                if (lane >= dlt) incl += n;
            }
            if (lane == 63) wsum[wv] = incl;
            __syncthreads();
            int woff = 0;
            for (int wwi = 0; wwi < wv; wwi++) woff += wsum[wwi];
            int excl = incl - s + woff;
            pfx[2 * tid]     = excl;
            pfx[2 * tid + 1] = excl + a0;
            if (tid == 255) pfx[NKEY] = excl + s;
            __syncthreads();
            // -- phase 3: place records bucket-ordered in LDS --
            for (int i = tid; i < EPB1; i += 256) {
                unsigned v = kr[i];
                if (v != 0xFFFFFFFFu) {
                    int t = e0 + i;
                    int r = t / N_EDGES;
                    int key, pos;
                    unsigned rec;
                    if (side == 0) {
                        int e   = t - r * N_EDGES;
                        int src = edges[(size_t)(r * 2) * N_EDGES + e];   // L2-hot re-read
                        int bkt    = (int)(v >> 22);
                        int dstloc = (int)((v >> 12) & 0x3FFu);
                        key = r * NB + bkt;
                        pos = pfx[key] + (int)(v & 0xFFFu);
                        rec = (unsigned)src | ((unsigned)dstloc << 17);
                    } else {
                        int src = (int)(v >> 12);
                        key = r * NB + src / BW;
                        pos = pfx[key] + (int)(v & 0xFFFu);
                        rec = (unsigned)src;
                    }
                    sorted[pos] = rec;
                    keyp[pos]   = (unsigned short)key;
                }
            }
            __syncthreads();
            // -- phase 4: coalesced write-out --
            {
                unsigned* out = side == 0 ? bktd : bkts;
                int tot = pfx[NKEY];
                for (int j = tid; j < tot; j += 256) {
                    int k   = keyp[j];
                    int idx = gb[k] + (j - pfx[k]);
                    if (idx < CAP) out[(size_t)k * CAP + idx] = sorted[j];
                }
            }
            __syncthreads();
        }
    } else if (b < B1_BLKS + XC_BLKS) {
        int t = (b - B1_BLKS) * 256 + threadIdx.x;
        float4 v = ((const float4*)X)[t];
        union { unsigned short u[4]; uint2 d; } o;
        o.u[0] = f2bf(v.x); o.u[1] = f2bf(v.y); o.u[2] = f2bf(v.z); o.u[3] = f2bf(v.w);
        ((uint2*)Xb)[t] = o.d;
    } else {
        int t = (b - B1_BLKS - XC_BLKS) * 256 + threadIdx.x;
        int r = t >> 14;
        int k = (t >> 7) & 127;
        int n = t & 127;
        Wt[(size_t)n * KTOT + r * D + k] = f2bf(W[t]);
    }
}

// ---------------------------------------------------------------------------
// 2a) src-bucket histogram -> rsqrt(outdeg) table (needed before 2b embeds c)
// ---------------------------------------------------------------------------
__global__ __launch_bounds__(1024) void pass2a(const int* __restrict__ gcur,
                                               const unsigned* __restrict__ bkts,
                                               float* __restrict__ routf) {
    __shared__ int cur[BW];
    int b = blockIdx.x, tid = threadIdx.x;
    if (tid < BW) cur[tid] = 0;
    __syncthreads();
    int r = b >> 7;
    int node0 = (b & 127) * BW;
    int cnt = min(gcur[(NKEY + b) * 16], CAP);
    for (int i = tid; i < cnt; i += 1024)
        atomicAdd(&cur[(int)bkts[(size_t)b * CAP + i] - node0], 1);
    __syncthreads();
    int nN = min(BW, N_NODES - node0);
    if (tid < nN) {
        int c = cur[tid];
        routf[r * N_NODES + node0 + tid] = rsqrtf((float)(c < 1 ? 1 : c));
    }
}

// ---------------------------------------------------------------------------
// 2b) ELL fill with LDS cursors; each slot stores (src, c=rout[src]) as uint2
//     so the gather's staging is a pure coalesced stream (no random lookups).
// ---------------------------------------------------------------------------
__global__ __launch_bounds__(1024) void pass2b(const int* __restrict__ gcur,
                                               const unsigned* __restrict__ bktd,
                                               const float* __restrict__ routf,
                                               uint2* __restrict__ esrcc,
                                               int* __restrict__ indeg) {
    __shared__ int cur[BW];
    int b = blockIdx.x, tid = threadIdx.x;
    if (tid < BW) cur[tid] = 0;
    __syncthreads();
    int r = b >> 7;
    int node0 = (b & 127) * BW;
    int cnt = min(gcur[b * 16], CAP);
    for (int i = tid; i < cnt; i += 1024) {
        unsigned rec = bktd[(size_t)b * CAP + i];
        int s      = (int)(rec & 0x1FFFFu);
        int dstloc = (int)(rec >> 17);
        int pos = atomicAdd(&cur[dstloc], 1);
        if (pos < MAXDEG) {
            union { float f; unsigned u; } c; c.f = routf[r * N_NODES + s];
            esrcc[((size_t)r * N_NODES + node0 + dstloc) * MAXDEG + pos] = make_uint2((unsigned)s, c.u);
        }
    }
    __syncthreads();
    int nN = min(BW, N_NODES - node0);
    if (tid < nN) indeg[r * N_NODES + node0 + tid] = cur[tid];
}

// ---------------------------------------------------------------------------
// 3) Fused 4-relation gather (known-good 110us): two dst nodes per wave,
//    32 lanes x 8B row loads, branchless inner loop, pre-built (src,c).
// ---------------------------------------------------------------------------
__global__ __launch_bounds__(256) void gather_ell(const uint2* __restrict__ esrcc,
                                                  const int* __restrict__ indeg,
                                                  const uint2* __restrict__ Xv,
                                                  uint2* __restrict__ A2) {
    __shared__ uint2 meta[8][N_REL][MAXDEG];   // {src, c_bits}, 8 KB
    int tid = threadIdx.x;
    int h   = tid >> 5;              // half-wave 0..7 -> node
    int l31 = tid & 31;
    int d   = blockIdx.x * 8 + h;    // grid = N_NODES/8 exactly

    int   n[N_REL];
    float rin[N_REL];
    int nm = 0;
#pragma unroll
    for (int r = 0; r < N_REL; r++) {
        int ind = indeg[r * N_NODES + d];
        n[r]   = ind > MAXDEG ? MAXDEG : ind;
        rin[r] = rsqrtf((float)(ind < 1 ? 1 : ind));
        nm = max(nm, n[r]);
        uint2 m = make_uint2(0u, 0u);
        if (l31 < n[r])
            m = esrcc[((size_t)r * N_NODES + d) * MAXDEG + l31];
        meta[h][r][l31] = m;
    }
    int nmax = max(nm, __shfl_xor(nm, 32));    // wave trip count (both nodes)
    __syncthreads();

    float4 acc[N_REL];
#pragma unroll
    for (int r = 0; r < N_REL; r++) acc[r] = make_float4(0.f, 0.f, 0.f, 0.f);

#pragma unroll 4
    for (int i = 0; i < nmax; i++) {
        uint2 m[N_REL];
#pragma unroll
        for (int r = 0; r < N_REL; r++) m[r] = meta[h][r][i];   // broadcast per half
        uint2 v[N_REL];
#pragma unroll
        for (int r = 0; r < N_REL; r++)
            v[r] = Xv[(size_t)m[r].x * (D / 4) + l31];           // 8B/lane
#pragma unroll
        for (int r = 0; r < N_REL; r++) {
            union { unsigned u; float f; } cc; cc.u = m[r].y;
            union { unsigned u; float f; } a, b, e, g;
            a.u = v[r].x << 16; b.u = v[r].x & 0xFFFF0000u;
            e.u = v[r].y << 16; g.u = v[r].y & 0xFFFF0000u;
            acc[r].x += cc.f * a.f;
            acc[r].y += cc.f * b.f;
            acc[r].z += cc.f * e.f;
            acc[r].w += cc.f * g.f;
        }
    }

#pragma unroll
    for (int r = 0; r < N_REL; r++) {
        unsigned p0 = (unsigned)f2bf(rin[r] * acc[r].x) | ((unsigned)f2bf(rin[r] * acc[r].y) << 16);
        unsigned p1 = (unsigned)f2bf(rin[r] * acc[r].z) | ((unsigned)f2bf(rin[r] * acc[r].w) << 16);
        A2[(size_t)d * (KTOT / 4) + r * (D / 4) + l31] = make_uint2(p0, p1);
    }
}

// ---------------------------------------------------------------------------
// 4) Final GEMM v2: 64-row tiles (was 128). 1564 blocks -> ~6 blocks/CU;
//    acc[8] = 32 VGPR/wave + launch_bounds(256,6) -> ~6 waves/SIMD (was 3).
//    The old version was latency-bound at 2.0 TB/s (76us, 3x its 27us
//    streaming floor) with only 3 waves/SIMD to hide ~600-900cy A-loads.
// ---------------------------------------------------------------------------
__global__ __launch_bounds__(256, 6) void gemm_mfma(const unsigned short* __restrict__ A,
                                                    const unsigned short* __restrict__ Wt,
                                                    float* __restrict__ Z) {
    int w    = threadIdx.x >> 6;     // wave 0..3 -> 16-row strip
    int lane = threadIdx.x & 63;
    int l15  = lane & 15;
    int quad = lane >> 4;
    int row0 = blockIdx.x * 64 + w * 16;

    f32x4 acc[8];
#pragma unroll
    for (int j = 0; j < 8; j++) acc[j] = (f32x4){0.f, 0.f, 0.f, 0.f};

#pragma unroll 4
    for (int k0 = 0; k0 < KTOT; k0 += 32) {
        bf16x8 a = *(const bf16x8*)(A + (size_t)(row0 + l15) * KTOT + k0 + quad * 8);
#pragma unroll
        for (int j = 0; j < 8; j++) {
            bf16x8 b = *(const bf16x8*)(Wt + (size_t)(j * 16 + l15) * KTOT + k0 + quad * 8);
            acc[j] = __builtin_amdgcn_mfma_f32_16x16x32_bf16(a, b, acc[j], 0, 0, 0);
        }
    }

    // C/D layout: col = lane&15, row = quad*4 + reg
#pragma unroll
    for (int reg = 0; reg < 4; reg++) {
        int row = row0 + quad * 4 + reg;
        if (row < N_NODES) {
#pragma unroll
            for (int j = 0; j < 8; j++)
                Z[(size_t)row * D + j * 16 + l15] = acc[j][reg];
        }
    }
}

// ---------------------------------------------------------------------------
extern "C" void kernel_launch(void* const* d_in, const int* in_sizes, int n_in,
                              void* d_out, int out_size, void* d_ws, size_t ws_size,
                              hipStream_t stream) {
    const int*   edges = (const int*)d_in[0];
    const float* X     = (const float*)d_in[1];
    const float* W     = (const float*)d_in[2];
    float*       Z     = (float*)d_out;

    auto align256 = [](size_t x) { return (x + 255) & ~(size_t)255; };
    char* ws = (char*)d_ws;
    size_t off = 0;
    int* gcur          = (int*)(ws + off);            off = align256(off + (size_t)2 * NKEY * 16 * sizeof(int));
    int* indeg         = (int*)(ws + off);            off = align256(off + (size_t)N_REL * N_NODES * sizeof(int));
    float* routf       = (float*)(ws + off);          off = align256(off + (size_t)N_REL * N_NODES * sizeof(float));
    uint2* esrcc       = (uint2*)(ws + off);          off = align256(off + (size_t)N_REL * N_NODES * MAXDEG * sizeof(uint2));
    unsigned short* Xb = (unsigned short*)(ws + off); off = align256(off + (size_t)N_NODES * D * sizeof(short));
    unsigned short* Wt = (unsigned short*)(ws + off); off = align256(off + (size_t)KTOT * D * sizeof(short));
    unsigned short* A  = (unsigned short*)(ws + off); off = align256(off + (size_t)M_PAD * KTOT * sizeof(short));
    // bucket arrays overlay A's region: dead before gather writes A.
    unsigned* bktd = (unsigned*)A;                                             // NKEY*CAP*4B = 11.5 MB
    unsigned* bkts = (unsigned*)((char*)A + (size_t)NKEY * CAP * sizeof(unsigned));  // +11.5 MB

    // only the 64 KB padded range-reservation counters need zeroing
    hipMemsetAsync(gcur, 0, (size_t)2 * NKEY * 16 * sizeof(int), stream);

    pass1<<<B1_BLKS + XC_BLKS + WC_BLKS, 256, 0, stream>>>(
        edges, gcur, bktd, bkts, X, Xb, W, Wt);

    pass2a<<<NKEY, 1024, 0, stream>>>(gcur, bkts, routf);

    pass2b<<<NKEY, 1024, 0, stream>>>(gcur, bktd, routf, esrcc, indeg);

    gather_ell<<<N_NODES / 8, 256, 0, stream>>>(
        esrcc, indeg, (const uint2*)Xb, (uint2*)A);

    gemm_mfma<<<M_PAD / 64, 256, 0, stream>>>(A, Wt, Z);
}

// Round 10
// 326.140 us; speedup vs baseline: 1.2361x; 1.2361x over previous
//
#include <hip/hip_runtime.h>
#include <hip/hip_bf16.h>

constexpr int N_NODES = 100000;
constexpr int N_REL   = 4;
constexpr int N_EDGES = 600000;
constexpr int MAXDEG  = 32;          // Poisson(6): P(deg>=32) ~ 7e-14 per node
constexpr int D       = 128;
constexpr int KTOT    = N_REL * D;   // 512 concat cols of A
constexpr int M_PAD   = 100096;      // 782 gemm blocks * 128 rows

// ---- bucketed-build geometry ----
constexpr int NB   = 128;            // buckets per relation
constexpr int BW   = 784;            // node width per bucket (128*784 = 100352 >= 100000)
constexpr int NKEY = N_REL * NB;     // 512 (r,bucket) keys
constexpr int CAP  = 5632;           // per-bucket capacity: mu=4704, sigma=68 -> +13.6 sigma
constexpr int EPB1 = 4096;           // edges per pass-1 block
constexpr int TOT_E   = N_REL * N_EDGES;              // 2.4M
constexpr int B1_BLKS = (TOT_E + EPB1 - 1) / EPB1;    // 586
constexpr int XC_BLKS = (N_NODES * D / 4) / 256;      // 12500
constexpr int WC_BLKS = (N_REL * D * D) / 256;        // 256

typedef __attribute__((ext_vector_type(8))) short bf16x8;   // MFMA A/B frag (4 VGPRs)
typedef __attribute__((ext_vector_type(4))) float f32x4;    // MFMA C/D frag

static __device__ __forceinline__ unsigned short f2bf(float f) {
    union { float f; unsigned int u; } v; v.f = f;
    unsigned int r = (v.u + 0x7fffu + ((v.u >> 16) & 1u)) >> 16;  // RNE
    return (unsigned short)r;
}

// ---------------------------------------------------------------------------
// 1) Pass 1 (counting-sort): per 4096-edge block, per side (dst/src): rank
//    via LDS histogram -> ONE reservation atomic per (block,key) -> place
//    records bucket-ordered in LDS -> coalesced write-out. Casts ride along.
// ---------------------------------------------------------------------------
__global__ __launch_bounds__(256) void pass1(const int* __restrict__ edges,
                                             int* __restrict__ gcur,        // [2*NKEY*16] padded counters
                                             unsigned* __restrict__ bktd,   // [NKEY*CAP] packed (src,dstloc)
                                             unsigned* __restrict__ bkts,   // [NKEY*CAP] src only
                                             const float* __restrict__ X,
                                             unsigned short* __restrict__ Xb,
                                             const float* __restrict__ W,
                                             unsigned short* __restrict__ Wt) {
    int b = blockIdx.x;
    if (b < B1_BLKS) {
        __shared__ unsigned kr[EPB1];         // 16KB per-slot stash
        __shared__ unsigned sorted[EPB1];     // 16KB records by position
        __shared__ unsigned short keyp[EPB1]; // 8KB  key by position
        __shared__ int h[NKEY], gb[NKEY], pfx[NKEY + 1];
        __shared__ int wsum[4];
        int tid  = threadIdx.x;
        int lane = tid & 63, wv = tid >> 6;
        int e0   = b * EPB1;
        int nval = min(EPB1, TOT_E - e0);

        for (int side = 0; side < 2; side++) {
            for (int k = tid; k < NKEY; k += 256) h[k] = 0;
            __syncthreads();
            // -- phase 1: rank assignment + stash --
            for (int i = tid; i < EPB1; i += 256) {
                unsigned v = 0xFFFFFFFFu;
                if (i < nval) {
                    int t = e0 + i;
                    int r = t / N_EDGES, e = t - r * N_EDGES;
                    if (side == 0) {
                        int dst = edges[(size_t)(r * 2 + 1) * N_EDGES + e];
                        int bkt = dst / BW;
                        int dstloc = dst - bkt * BW;
                        int rank = atomicAdd(&h[r * NB + bkt], 1);
                        v = ((unsigned)bkt << 22) | ((unsigned)dstloc << 12) | (unsigned)rank;
                    } else {
                        int src = edges[(size_t)(r * 2) * N_EDGES + e];
                        int bkt = src / BW;
                        int rank = atomicAdd(&h[r * NB + bkt], 1);
                        v = ((unsigned)src << 12) | (unsigned)rank;
                    }
                }
                kr[i] = v;
            }
            __syncthreads();
            // -- phase 2: global reservation + parallel prefix over h --
            for (int k = tid; k < NKEY; k += 256) {
                int c = h[k];
                gb[k] = c ? atomicAdd(&gcur[(side * NKEY + k) * 16], c) : 0;
            }
            int a0 = h[2 * tid], a1 = h[2 * tid + 1];
            int s  = a0 + a1;
            int incl = s;
#pragma unroll
            for (int dlt = 1; dlt < 64; dlt <<= 1) {
                int n = __shfl_up(incl, dlt);
                if (lane >= dlt) incl += n;
            }
            if (lane == 63) wsum[wv] = incl;
            __syncthreads();
            int woff = 0;
            for (int wwi = 0; wwi < wv; wwi++) woff += wsum[wwi];
            int excl = incl - s + woff;
            pfx[2 * tid]     = excl;
            pfx[2 * tid + 1] = excl + a0;
            if (tid == 255) pfx[NKEY] = excl + s;
            __syncthreads();
            // -- phase 3: place records bucket-ordered in LDS --
            for (int i = tid; i < EPB1; i += 256) {
                unsigned v = kr[i];
                if (v != 0xFFFFFFFFu) {
                    int t = e0 + i;
                    int r = t / N_EDGES;
                    int key, pos;
                    unsigned rec;
                    if (side == 0) {
                        int e   = t - r * N_EDGES;
                        int src = edges[(size_t)(r * 2) * N_EDGES + e];   // L2-hot re-read
                        int bkt    = (int)(v >> 22);
                        int dstloc = (int)((v >> 12) & 0x3FFu);
                        key = r * NB + bkt;
                        pos = pfx[key] + (int)(v & 0xFFFu);
                        rec = (unsigned)src | ((unsigned)dstloc << 17);
                    } else {
                        int src = (int)(v >> 12);
                        key = r * NB + src / BW;
                        pos = pfx[key] + (int)(v & 0xFFFu);
                        rec = (unsigned)src;
                    }
                    sorted[pos] = rec;
                    keyp[pos]   = (unsigned short)key;
                }
            }
            __syncthreads();
            // -- phase 4: coalesced write-out --
            {
                unsigned* out = side == 0 ? bktd : bkts;
                int tot = pfx[NKEY];
                for (int j = tid; j < tot; j += 256) {
                    int k   = keyp[j];
                    int idx = gb[k] + (j - pfx[k]);
                    if (idx < CAP) out[(size_t)k * CAP + idx] = sorted[j];
                }
            }
            __syncthreads();
        }
    } else if (b < B1_BLKS + XC_BLKS) {
        int t = (b - B1_BLKS) * 256 + threadIdx.x;
        float4 v = ((const float4*)X)[t];
        union { unsigned short u[4]; uint2 d; } o;
        o.u[0] = f2bf(v.x); o.u[1] = f2bf(v.y); o.u[2] = f2bf(v.z); o.u[3] = f2bf(v.w);
        ((uint2*)Xb)[t] = o.d;
    } else {
        int t = (b - B1_BLKS - XC_BLKS) * 256 + threadIdx.x;
        int r = t >> 14;
        int k = (t >> 7) & 127;
        int n = t & 127;
        Wt[(size_t)n * KTOT + r * D + k] = f2bf(W[t]);
    }
}

// ---------------------------------------------------------------------------
// 2a) src-bucket histogram -> rsqrt(outdeg) table (needed before 2b embeds c)
// ---------------------------------------------------------------------------
__global__ __launch_bounds__(1024) void pass2a(const int* __restrict__ gcur,
                                               const unsigned* __restrict__ bkts,
                                               float* __restrict__ routf) {
    __shared__ int cur[BW];
    int b = blockIdx.x, tid = threadIdx.x;
    if (tid < BW) cur[tid] = 0;
    __syncthreads();
    int r = b >> 7;
    int node0 = (b & 127) * BW;
    int cnt = min(gcur[(NKEY + b) * 16], CAP);
    for (int i = tid; i < cnt; i += 1024)
        atomicAdd(&cur[(int)bkts[(size_t)b * CAP + i] - node0], 1);
    __syncthreads();
    int nN = min(BW, N_NODES - node0);
    if (tid < nN) {
        int c = cur[tid];
        routf[r * N_NODES + node0 + tid] = rsqrtf((float)(c < 1 ? 1 : c));
    }
}

// ---------------------------------------------------------------------------
// 2b) ELL fill with LDS cursors; each slot stores (src, c=rout[src]) as uint2
//     so the gather's staging is a pure coalesced stream (no random lookups).
// ---------------------------------------------------------------------------
__global__ __launch_bounds__(1024) void pass2b(const int* __restrict__ gcur,
                                               const unsigned* __restrict__ bktd,
                                               const float* __restrict__ routf,
                                               uint2* __restrict__ esrcc,
                                               int* __restrict__ indeg) {
    __shared__ int cur[BW];
    int b = blockIdx.x, tid = threadIdx.x;
    if (tid < BW) cur[tid] = 0;
    __syncthreads();
    int r = b >> 7;
    int node0 = (b & 127) * BW;
    int cnt = min(gcur[b * 16], CAP);
    for (int i = tid; i < cnt; i += 1024) {
        unsigned rec = bktd[(size_t)b * CAP + i];
        int s      = (int)(rec & 0x1FFFFu);
        int dstloc = (int)(rec >> 17);
        int pos = atomicAdd(&cur[dstloc], 1);
        if (pos < MAXDEG) {
            union { float f; unsigned u; } c; c.f = routf[r * N_NODES + s];
            esrcc[((size_t)r * N_NODES + node0 + dstloc) * MAXDEG + pos] = make_uint2((unsigned)s, c.u);
        }
    }
    __syncthreads();
    int nN = min(BW, N_NODES - node0);
    if (tid < nN) indeg[r * N_NODES + node0 + tid] = cur[tid];
}

// ---------------------------------------------------------------------------
// 3) Fused 4-relation gather (known-good 110us): two dst nodes per wave,
//    32 lanes x 8B row loads, branchless inner loop, pre-built (src,c).
// ---------------------------------------------------------------------------
__global__ __launch_bounds__(256) void gather_ell(const uint2* __restrict__ esrcc,
                                                  const int* __restrict__ indeg,
                                                  const uint2* __restrict__ Xv,
                                                  uint2* __restrict__ A2) {
    __shared__ uint2 meta[8][N_REL][MAXDEG];   // {src, c_bits}, 8 KB
    int tid = threadIdx.x;
    int h   = tid >> 5;              // half-wave 0..7 -> node
    int l31 = tid & 31;
    int d   = blockIdx.x * 8 + h;    // grid = N_NODES/8 exactly

    int   n[N_REL];
    float rin[N_REL];
    int nm = 0;
#pragma unroll
    for (int r = 0; r < N_REL; r++) {
        int ind = indeg[r * N_NODES + d];
        n[r]   = ind > MAXDEG ? MAXDEG : ind;
        rin[r] = rsqrtf((float)(ind < 1 ? 1 : ind));
        nm = max(nm, n[r]);
        uint2 m = make_uint2(0u, 0u);
        if (l31 < n[r])
            m = esrcc[((size_t)r * N_NODES + d) * MAXDEG + l31];
        meta[h][r][l31] = m;
    }
    int nmax = max(nm, __shfl_xor(nm, 32));    // wave trip count (both nodes)
    __syncthreads();

    float4 acc[N_REL];
#pragma unroll
    for (int r = 0; r < N_REL; r++) acc[r] = make_float4(0.f, 0.f, 0.f, 0.f);

#pragma unroll 4
    for (int i = 0; i < nmax; i++) {
        uint2 m[N_REL];
#pragma unroll
        for (int r = 0; r < N_REL; r++) m[r] = meta[h][r][i];   // broadcast per half
        uint2 v[N_REL];
#pragma unroll
        for (int r = 0; r < N_REL; r++)
            v[r] = Xv[(size_t)m[r].x * (D / 4) + l31];           // 8B/lane
#pragma unroll
        for (int r = 0; r < N_REL; r++) {
            union { unsigned u; float f; } cc; cc.u = m[r].y;
            union { unsigned u; float f; } a, b, e, g;
            a.u = v[r].x << 16; b.u = v[r].x & 0xFFFF0000u;
            e.u = v[r].y << 16; g.u = v[r].y & 0xFFFF0000u;
            acc[r].x += cc.f * a.f;
            acc[r].y += cc.f * b.f;
            acc[r].z += cc.f * e.f;
            acc[r].w += cc.f * g.f;
        }
    }

#pragma unroll
    for (int r = 0; r < N_REL; r++) {
        unsigned p0 = (unsigned)f2bf(rin[r] * acc[r].x) | ((unsigned)f2bf(rin[r] * acc[r].y) << 16);
        unsigned p1 = (unsigned)f2bf(rin[r] * acc[r].z) | ((unsigned)f2bf(rin[r] * acc[r].w) << 16);
        A2[(size_t)d * (KTOT / 4) + r * (D / 4) + l31] = make_uint2(p0, p1);
    }
}

// ---------------------------------------------------------------------------
// 4) GEMM v3: 128-row blocks, Wt staged in LDS per 128-col k-chunk (32 KB,
//    XOR-swizzled byte^=(row&7)<<4 -- the proven round-5 pattern). B-frags
//    become ~30cy LDS reads; the only k-loop global loads are streaming
//    A-frags (8 independent/step-pair -> MLP). Fixes R9's VGPR-starved
//    serial-load regression (VGPR=36, MfmaUtil 4%, 120us) AND R4's L2
//    latency-bound Wt streaming (400MB L2, 76us). No launch_bounds cap.
// ---------------------------------------------------------------------------
__global__ __launch_bounds__(256) void gemm_mfma(const unsigned short* __restrict__ A,
                                                 const unsigned short* __restrict__ Wt,
                                                 float* __restrict__ Z) {
    __shared__ unsigned short Bt[128 * 128];   // 32 KB: 128 j-rows x 256B, swizzled
    int tid  = threadIdx.x;
    int w    = tid >> 6;
    int lane = tid & 63;
    int l15  = lane & 15;
    int quad = lane >> 4;
    int row0 = blockIdx.x * 128 + w * 32;

    f32x4 acc[2][8];
#pragma unroll
    for (int m = 0; m < 2; m++)
#pragma unroll
        for (int j = 0; j < 8; j++) acc[m][j] = (f32x4){0.f, 0.f, 0.f, 0.f};

    for (int kc = 0; kc < 4; kc++) {
        __syncthreads();               // previous chunk's readers done
        // stage Wt[0..128)[kc*128 .. kc*128+128) -> Bt (16B per thread x 8)
#pragma unroll
        for (int i = 0; i < 8; i++) {
            int idx = tid + i * 256;   // 0..2047 16B-chunks
            int j   = idx >> 4;        // j-row
            int c16 = idx & 15;        // 16B chunk within 256B row
            uint4 v = *(const uint4*)(Wt + (size_t)j * KTOT + kc * 128 + c16 * 8);
            unsigned off = (unsigned)j * 256u + (((unsigned)c16 * 16u) ^ ((unsigned)(j & 7) << 4));
            *(uint4*)((char*)Bt + off) = v;
        }
        __syncthreads();
        // 4 k0-steps on this chunk; A from global (streams, L3-hot)
#pragma unroll
        for (int kk = 0; kk < 4; kk++) {
            int k0 = kc * 128 + kk * 32;
            bf16x8 a[2];
#pragma unroll
            for (int m = 0; m < 2; m++)
                a[m] = *(const bf16x8*)(A + (size_t)(row0 + m * 16 + l15) * KTOT + k0 + quad * 8);
#pragma unroll
            for (int j = 0; j < 8; j++) {
                int brow = j * 16 + l15;
                unsigned boff = (unsigned)brow * 256u +
                                (((unsigned)(kk * 64 + quad * 16)) ^ ((unsigned)(brow & 7) << 4));
                bf16x8 b = *(const bf16x8*)((const char*)Bt + boff);
                acc[0][j] = __builtin_amdgcn_mfma_f32_16x16x32_bf16(a[0], b, acc[0][j], 0, 0, 0);
                acc[1][j] = __builtin_amdgcn_mfma_f32_16x16x32_bf16(a[1], b, acc[1][j], 0, 0, 0);
            }
        }
    }

    // C/D layout: col = lane&15, row = quad*4 + reg
#pragma unroll
    for (int m = 0; m < 2; m++)
#pragma unroll
        for (int reg = 0; reg < 4; reg++) {
            int row = row0 + m * 16 + quad * 4 + reg;
            if (row < N_NODES) {
#pragma unroll
                for (int j = 0; j < 8; j++)
                    Z[(size_t)row * D + j * 16 + l15] = acc[m][j][reg];
            }
        }
}

// ---------------------------------------------------------------------------
extern "C" void kernel_launch(void* const* d_in, const int* in_sizes, int n_in,
                              void* d_out, int out_size, void* d_ws, size_t ws_size,
                              hipStream_t stream) {
    const int*   edges = (const int*)d_in[0];
    const float* X     = (const float*)d_in[1];
    const float* W     = (const float*)d_in[2];
    float*       Z     = (float*)d_out;

    auto align256 = [](size_t x) { return (x + 255) & ~(size_t)255; };
    char* ws = (char*)d_ws;
    size_t off = 0;
    int* gcur          = (int*)(ws + off);            off = align256(off + (size_t)2 * NKEY * 16 * sizeof(int));
    int* indeg         = (int*)(ws + off);            off = align256(off + (size_t)N_REL * N_NODES * sizeof(int));
    float* routf       = (float*)(ws + off);          off = align256(off + (size_t)N_REL * N_NODES * sizeof(float));
    uint2* esrcc       = (uint2*)(ws + off);          off = align256(off + (size_t)N_REL * N_NODES * MAXDEG * sizeof(uint2));
    unsigned short* Xb = (unsigned short*)(ws + off); off = align256(off + (size_t)N_NODES * D * sizeof(short));
    unsigned short* Wt = (unsigned short*)(ws + off); off = align256(off + (size_t)KTOT * D * sizeof(short));
    unsigned short* A  = (unsigned short*)(ws + off); off = align256(off + (size_t)M_PAD * KTOT * sizeof(short));
    // bucket arrays overlay A's region: dead before gather writes A.
    unsigned* bktd = (unsigned*)A;                                             // NKEY*CAP*4B = 11.5 MB
    unsigned* bkts = (unsigned*)((char*)A + (size_t)NKEY * CAP * sizeof(unsigned));  // +11.5 MB

    // only the 64 KB padded range-reservation counters need zeroing
    hipMemsetAsync(gcur, 0, (size_t)2 * NKEY * 16 * sizeof(int), stream);

    pass1<<<B1_BLKS + XC_BLKS + WC_BLKS, 256, 0, stream>>>(
        edges, gcur, bktd, bkts, X, Xb, W, Wt);

    pass2a<<<NKEY, 1024, 0, stream>>>(gcur, bkts, routf);

    pass2b<<<NKEY, 1024, 0, stream>>>(gcur, bktd, routf, esrcc, indeg);

    gather_ell<<<N_NODES / 8, 256, 0, stream>>>(
        esrcc, indeg, (const uint2*)Xb, (uint2*)A);

    gemm_mfma<<<M_PAD / 128, 256, 0, stream>>>(A, Wt, Z);
}